// Round 13
// baseline (807.305 us; speedup 1.0000x reference)
//
#include <hip/hip_runtime.h>
#include <math.h>

#define NHh   16
#define QL    1024
#define KL    2048
#define SCALEh 0.125f

typedef __attribute__((ext_vector_type(8))) short s8v;
typedef __attribute__((ext_vector_type(4))) float f4v;

#define MFMA16(a,b,c) __builtin_amdgcn_mfma_f32_16x16x32_bf16((a),(b),(c),0,0,0)

__device__ __forceinline__ short f2bf(float x) {
  unsigned u = __float_as_uint(x);
  return (short)((u + 0x7fffu + ((u >> 16) & 1u)) >> 16);
}
__device__ __forceinline__ float bf2f(short s) {
  return __uint_as_float(((unsigned)(unsigned short)s) << 16);
}

// ---------------------------------------------------------------------------
// split-bf16 MFMA GEMM: C[m][n] = sum_k A[m][k]*Bmat[n][k], K=1024, tile 128x128
// MODE0: A=[mems;w] (M=4096), N=3072; epilogue: Qw/Qr hi/lo (+bias), K hi/lo, V^T bf16
// MODE1: A=r (M=2048), N=1024; epilogue: RK hi/lo [head][row][d]
// MODE2: A=(avp0+avp1)*linv_row; epilogue: out fp32
// LDS XOR swizzle: slot = row*8 + (kgroup ^ (row&7))
// ---------------------------------------------------------------------------
template<int MODE>
__global__ __launch_bounds__(256)
void gemm_mfma(const float* __restrict__ A0, const float* __restrict__ A1,
               const float* __restrict__ Bmat,
               short* __restrict__ P0h, short* __restrict__ P0l,
               short* __restrict__ P1h, short* __restrict__ P1l,
               short* __restrict__ P2h, short* __restrict__ P2l,
               short* __restrict__ P3,
               float* __restrict__ Ofp,
               const float* __restrict__ rwb, const float* __restrict__ rrb,
               const float* __restrict__ Wl)
{
  __shared__ short Ah[128*64];
  __shared__ short Al[128*64];
  __shared__ short Bh[128*64];
  __shared__ short Bl[128*64];
  const int n0 = blockIdx.x * 128, m0 = blockIdx.y * 128;
  if (MODE == 0 && n0 < 1024 && m0 < 2048) return;   // q rows t<1024 are discarded
  const int tid = threadIdx.x;
  const int L = tid & 63, lr = L & 15, lg = L >> 4;
  const int wid = tid >> 6, wm = wid >> 1, wn = wid & 1;
  const int srow = tid >> 1, sseg = tid & 1;

  const float* arow;
  const float* arow2 = nullptr;
  if (MODE == 0) {
    int m = m0 + srow;
    arow = (m < 2048) ? (A0 + (size_t)m * 1024) : (A1 + (size_t)(m - 2048) * 1024);
  } else {
    arow = A0 + (size_t)(m0 + srow) * 1024;
    if (MODE == 2) arow2 = A1 + (size_t)(m0 + srow) * 1024;
  }
  const float* brow = Bmat + (size_t)(n0 + srow) * 1024;

  const f4v fz = {0.f, 0.f, 0.f, 0.f};
  f4v acc[4][4];
#pragma unroll
  for (int a = 0; a < 4; ++a)
#pragma unroll
    for (int bq = 0; bq < 4; ++bq) acc[a][bq] = fz;

  for (int k0 = 0; k0 < 1024; k0 += 64) {
    __syncthreads();
    {
      float wgt = 1.0f;
      if (MODE == 2) {
        int m = m0 + srow;
        wgt = Wl[((size_t)((m & 1) * NHh) + (k0 >> 6)) * 1024 + (m >> 1)];
      }
      const float* pa = arow + k0 + sseg * 32;
#pragma unroll
      for (int v = 0; v < 4; ++v) {
        float4 f0 = *reinterpret_cast<const float4*>(pa + v * 8);
        float4 f1 = *reinterpret_cast<const float4*>(pa + v * 8 + 4);
        if (MODE == 2) {
          const float* pa2 = arow2 + k0 + sseg * 32;
          float4 g0 = *reinterpret_cast<const float4*>(pa2 + v * 8);
          float4 g1 = *reinterpret_cast<const float4*>(pa2 + v * 8 + 4);
          f0.x = (f0.x + g0.x) * wgt; f0.y = (f0.y + g0.y) * wgt;
          f0.z = (f0.z + g0.z) * wgt; f0.w = (f0.w + g0.w) * wgt;
          f1.x = (f1.x + g1.x) * wgt; f1.y = (f1.y + g1.y) * wgt;
          f1.z = (f1.z + g1.z) * wgt; f1.w = (f1.w + g1.w) * wgt;
        }
        float bf[8] = {f0.x, f0.y, f0.z, f0.w, f1.x, f1.y, f1.z, f1.w};
        s8v hi, lo;
#pragma unroll
        for (int e = 0; e < 8; ++e) {
          short h = f2bf(bf[e]); hi[e] = h; lo[e] = f2bf(bf[e] - bf2f(h));
        }
        int slot = srow * 8 + ((sseg * 4 + v) ^ (srow & 7));
        *reinterpret_cast<s8v*>(Ah + slot * 8) = hi;
        *reinterpret_cast<s8v*>(Al + slot * 8) = lo;
      }
      const float* pb = brow + k0 + sseg * 32;
#pragma unroll
      for (int v = 0; v < 4; ++v) {
        float4 f0 = *reinterpret_cast<const float4*>(pb + v * 8);
        float4 f1 = *reinterpret_cast<const float4*>(pb + v * 8 + 4);
        float bf[8] = {f0.x, f0.y, f0.z, f0.w, f1.x, f1.y, f1.z, f1.w};
        s8v hi, lo;
#pragma unroll
        for (int e = 0; e < 8; ++e) {
          short h = f2bf(bf[e]); hi[e] = h; lo[e] = f2bf(bf[e] - bf2f(h));
        }
        int slot = srow * 8 + ((sseg * 4 + v) ^ (srow & 7));
        *reinterpret_cast<s8v*>(Bh + slot * 8) = hi;
        *reinterpret_cast<s8v*>(Bl + slot * 8) = lo;
      }
    }
    __syncthreads();
#pragma unroll
    for (int ks = 0; ks < 2; ++ks) {
      s8v a_h[4], a_l[4], b_h[4], b_l[4];
#pragma unroll
      for (int x = 0; x < 4; ++x) {
        int ra = wm * 64 + x * 16 + lr;
        int sa = ra * 8 + ((ks * 4 + lg) ^ (ra & 7));
        a_h[x] = *reinterpret_cast<const s8v*>(Ah + sa * 8);
        a_l[x] = *reinterpret_cast<const s8v*>(Al + sa * 8);
        int rb = wn * 64 + x * 16 + lr;
        int sb = rb * 8 + ((ks * 4 + lg) ^ (rb & 7));
        b_h[x] = *reinterpret_cast<const s8v*>(Bh + sb * 8);
        b_l[x] = *reinterpret_cast<const s8v*>(Bl + sb * 8);
      }
#pragma unroll
      for (int mf = 0; mf < 4; ++mf)
#pragma unroll
        for (int nf = 0; nf < 4; ++nf) {
          acc[mf][nf] = MFMA16(a_l[mf], b_h[nf], acc[mf][nf]);
          acc[mf][nf] = MFMA16(a_h[mf], b_l[nf], acc[mf][nf]);
          acc[mf][nf] = MFMA16(a_h[mf], b_h[nf], acc[mf][nf]);
        }
    }
  }
  // ---- epilogue: C/D layout col=lane&15, row=(lane>>4)*4+reg (m89-verified)
  const int sec = (MODE == 0) ? (n0 >> 10) : 0;
#pragma unroll
  for (int mf = 0; mf < 4; ++mf)
#pragma unroll
    for (int nf = 0; nf < 4; ++nf) {
      const int n = n0 + wn * 64 + nf * 16 + lr;
#pragma unroll
      for (int r = 0; r < 4; ++r) {
        const int m = m0 + wm * 64 + mf * 16 + lg * 4 + r;
        float val = acc[mf][nf][r];
        if (MODE == 2) {
          Ofp[(size_t)m * 1024 + n] = val;
        } else if (MODE == 1) {
          int nn = n >> 6, d = n & 63;
          size_t idx = (((size_t)nn * KL + m) << 6) + d;
          short h = f2bf(val);
          P0h[idx] = h; P0l[idx] = f2bf(val - bf2f(h));
        } else {
          int b = m & 1, t = m >> 1;
          if (sec == 0) {                       // q section: t >= 1024 guaranteed
            int i = t - 1024;
            int nn = n >> 6, d = n & 63;
            size_t idx = (((size_t)(b * NHh + nn) * QL + i) << 6) + d;
            float qw = val + rwb[n];
            float qr = val + rrb[n];
            short h = f2bf(qw);
            P0h[idx] = h; P0l[idx] = f2bf(qw - bf2f(h));
            h = f2bf(qr);
            P1h[idx] = h; P1l[idx] = f2bf(qr - bf2f(h));
          } else if (sec == 1) {                // K
            int c = n - 1024; int nn = c >> 6, d = c & 63;
            size_t idx = (((size_t)(b * NHh + nn) * KL + t) << 6) + d;
            short h = f2bf(val);
            P2h[idx] = h; P2l[idx] = f2bf(val - bf2f(h));
          } else {                              // V^T single bf16 [bn][d][t]
            int c = n - 2048; int nn = c >> 6, d = c & 63;
            size_t idx = ((size_t)(b * NHh + nn) * 64 + d) * KL + t;
            P3[idx] = f2bf(val);
          }
        }
      }
    }
}

// ---------------------------------------------------------------------------
// Fused attention, single pass. LDS-staged via ASYNC global_load_lds (no VGPR
// destinations -> nothing for the compiler to sink or spill; m97 pattern).
// Grid 1024 = 8 xcd x 4 bn x 16 iblk x 2 ch (XCD L2 locality, FETCH 39 MB
// confirmed r10). Block = 256 thr = 4 waves; wave wv owns q-rows
// [i0+wv*16, i0+wv*16+16), i0 = iblk*64.
// Single 48KB KV buffer (Khi 8K | Klo 8K | RKhi 16K | RKlo 16K), slot layout
// slot = row*8 + (kg ^ (row&7)) achieved by PRE-SWIZZLING the per-lane GLOBAL
// address (m173): LDS dest of each 1KB call is the wave-uniform slot base,
// HW writes lane L at base + L*16. Compute body identical to the round-11
// refcheck-passed kernel. Two barriers/tile (m97 cadence); the co-resident
// second block/CU covers the stage drain (m114). Total LDS 81,408 B ->
// 2 blocks/CU. RK window BASE = 960-i0+j0 (128 rows); per-wave sub-window
// woff = 48-wv*16; gather cl = 15 - ir16 + jf*16 + lr.
// ---------------------------------------------------------------------------
__global__ __launch_bounds__(256, 2)
void attn_fused(const short* __restrict__ Qwh, const short* __restrict__ Qwl,
                const short* __restrict__ Qrh, const short* __restrict__ Qrl,
                const short* __restrict__ Kh,  const short* __restrict__ Klo,
                const short* __restrict__ RKh, const short* __restrict__ RKl,
                const short* __restrict__ Vb,
                float* __restrict__ prob,
                float* __restrict__ avp,
                float* __restrict__ lpart)
{
  __shared__ __align__(1024) char KV[49152];
  __shared__ float Gs[4][80 * 18];
  __shared__ short Ps[4][16 * 72];
  const int tid = threadIdx.x;
  const int wv = tid >> 6;
  const int L = tid & 63, lr = L & 15, lg = L >> 4;
  const int orig = blockIdx.x;
  const int xcd  = orig & 7;
  const int k2   = orig >> 3;               // 0..127
  const int bn   = xcd * 4 + (k2 >> 5);     // 0..31
  const int rest = k2 & 31;
  const int iblk = rest >> 1, ch = rest & 1;
  const int nh = bn & 15, b = bn >> 4;
  const int i0 = iblk * 64;
  const int woff = 48 - wv * 16;
  const f4v fz = {0.f, 0.f, 0.f, 0.f};

  int T = ((i0 + 1087) >> 6) + 1; if (T > 32) T = 32;
  const int t0 = (ch * T) >> 1;
  const int t1 = ((ch + 1) * T) >> 1;

  const size_t bnKL = (size_t)bn * KL;
  const size_t nhKL = (size_t)nh * KL;

  // Q A-frags (rows i0+wv*16+lr), held for the whole kernel
  s8v qw_h[2], qw_l[2], qr_h[2], qr_l[2];
#pragma unroll
  for (int ks = 0; ks < 2; ++ks) {
    size_t idx = (((size_t)bn * QL + i0 + wv * 16 + lr) << 6) + ks * 32 + lg * 8;
    qw_h[ks] = *reinterpret_cast<const s8v*>(Qwh + idx);
    qw_l[ks] = *reinterpret_cast<const s8v*>(Qwl + idx);
    qr_h[ks] = *reinterpret_cast<const s8v*>(Qrh + idx);
    qr_l[ks] = *reinterpret_cast<const s8v*>(Qrl + idx);
  }

  float lrun[4] = {0.f, 0.f, 0.f, 0.f};
  f4v av[4];
#pragma unroll
  for (int df = 0; df < 4; ++df) av[df] = fz;

  float* probb = prob + (size_t)bn * QL * KL;
  float* gs = &Gs[wv][0];
  short* ps = &Ps[wv][0];

  // ---- async staging: 3072 slots of 16B; wave wv issues 12 x 1KB calls.
  // Per-lane GLOBAL src carries the swizzle; LDS dest is the uniform slot base.
  auto stage = [&](int jtn) {
#pragma unroll
    for (int e = 0; e < 12; ++e) {
      const int sb = wv * 768 + e * 64;   // wave-uniform slot base
      const int s = sb + L;
      const int j0n = jtn * 64;
      const short* src;
      if (s < 1024) {                               // K hi | lo
        int s2 = s & 511;
        int row = s2 >> 3, kg = (s2 & 7) ^ (row & 7);
        const short* bp = (s < 512) ? Kh : Klo;
        src = bp + ((bnKL + j0n + row) << 6) + kg * 8;
      } else {                                      // RK hi | lo
        int s2 = (s - 1024) & 1023;
        int row = s2 >> 3, kg = (s2 & 7) ^ (row & 7);
        int rg = (960 - i0 + j0n) + row;
        rg = rg < 0 ? 0 : (rg > 2047 ? 2047 : rg);  // clamped rows feed masked elems only
        const short* bp = (s < 2048) ? RKh : RKl;
        src = bp + ((nhKL + rg) << 6) + kg * 8;
      }
      __builtin_amdgcn_global_load_lds(
          (const __attribute__((address_space(1))) void*)src,
          (__attribute__((address_space(3))) void*)(KV + sb * 16),
          16, 0, 0);
    }
  };

  stage(t0);   // prologue

  for (int jt = t0; jt < t1; ++jt) {
    const int j0 = jt * 64;
    __syncthreads();                     // drains vmcnt -> KV ready

    // ---- BD: 30 MFMAs from LDS RK window
    f4v gacc[5];
#pragma unroll
    for (int gi = 0; gi < 5; ++gi) gacc[gi] = fz;
#pragma unroll
    for (int ci = 0; ci < 5; ++ci) {
      int rowl = woff + ci * 16 + lr;
#pragma unroll
      for (int ks = 0; ks < 2; ++ks) {
        int slot = rowl * 8 + ((ks * 4 + lg) ^ (rowl & 7));
        s8v r_h = *reinterpret_cast<const s8v*>(KV + 16384 + slot * 16);
        s8v r_l = *reinterpret_cast<const s8v*>(KV + 32768 + slot * 16);
        gacc[ci] = MFMA16(qr_l[ks], r_h, gacc[ci]);
        gacc[ci] = MFMA16(qr_h[ks], r_l, gacc[ci]);
        gacc[ci] = MFMA16(qr_h[ks], r_h, gacc[ci]);
      }
    }
    // spill G to wave-private LDS: [c_local][i16], stride 18
#pragma unroll
    for (int gi = 0; gi < 5; ++gi)
      *reinterpret_cast<f4v*>(gs + (gi * 16 + lr) * 18 + lg * 4) = gacc[gi];

    // ---- AC: 24 MFMAs from LDS K tile
    f4v sfr[4];
#pragma unroll
    for (int jf = 0; jf < 4; ++jf) {
      sfr[jf] = fz;
      int rowk = jf * 16 + lr;
#pragma unroll
      for (int ks = 0; ks < 2; ++ks) {
        int slot = rowk * 8 + ((ks * 4 + lg) ^ (rowk & 7));
        s8v k_h = *reinterpret_cast<const s8v*>(KV + slot * 16);
        s8v k_l = *reinterpret_cast<const s8v*>(KV + 8192 + slot * 16);
        sfr[jf] = MFMA16(qw_l[ks], k_h, sfr[jf]);
        sfr[jf] = MFMA16(qw_h[ks], k_l, sfr[jf]);
        sfr[jf] = MFMA16(qw_h[ks], k_h, sfr[jf]);
      }
    }
    // ---- V frags issued NOW; latency hides under the exp/gather phase
    s8v vf[2][4];
#pragma unroll
    for (int ks = 0; ks < 2; ++ks)
#pragma unroll
      for (int df = 0; df < 4; ++df)
        vf[ks][df] = *reinterpret_cast<const s8v*>(
            Vb + ((size_t)bn * 64 + df * 16 + lr) * KL + j0 + ks * 32 + lg * 8);
    __builtin_amdgcn_sched_barrier(0);   // V loads may not sink below
    // ---- gather G, scores, p' = exp(s), write prob + Ps, accumulate l
#pragma unroll
    for (int jf = 0; jf < 4; ++jf) {
#pragma unroll
      for (int r = 0; r < 4; ++r) {
        const int ir16 = lg * 4 + r;
        const int i = i0 + wv * 16 + ir16;
        const int j = j0 + jf * 16 + lr;
        const int cl = 15 - ir16 + jf * 16 + lr;
        float s = (sfr[jf][r] + gs[cl * 18 + ir16]) * SCALEh;
        float p = (j <= i + 1024) ? __expf(s) : 0.f;
        probb[(size_t)i * KL + j] = p;
        ps[ir16 * 72 + jf * 16 + lr] = f2bf(p);
        lrun[r] += p;
      }
    }
    // ---- PV: AV'[i][d] += p' * V^T[d][j]
#pragma unroll
    for (int ks = 0; ks < 2; ++ks) {
      s8v pa = *reinterpret_cast<const s8v*>(ps + lr * 72 + ks * 32 + lg * 8);
#pragma unroll
      for (int df = 0; df < 4; ++df)
        av[df] = MFMA16(pa, vf[ks][df], av[df]);
    }
    __syncthreads();                     // all waves done reading KV
    if (jt + 1 < t1) stage(jt + 1);      // overwrite buffer for next tile
  }

  // ---- l partials: sum over the 16 lanes (lr) sharing each row
#pragma unroll
  for (int r = 0; r < 4; ++r) {
    float l = lrun[r];
#pragma unroll
    for (int mk = 1; mk <= 8; mk <<= 1) l += __shfl_xor(l, mk, 64);
    if (lr == 0) {
      int i = i0 + wv * 16 + lg * 4 + r;
      lpart[(size_t)ch * 32768 + (size_t)bn * QL + i] = l;
    }
  }
  // ---- AV' partials
#pragma unroll
  for (int df = 0; df < 4; ++df)
#pragma unroll
    for (int r = 0; r < 4; ++r) {
      int i = i0 + wv * 16 + lg * 4 + r;
      int d = df * 16 + lr;
      avp[(size_t)ch * 2097152 + ((size_t)i * 2 + b) * 1024 + nh * 64 + d] = av[df][r];
    }
}

// linv[row] = 1 / (lpart0[row] + lpart1[row]), in place into lpart0
__global__ __launch_bounds__(256)
void l_combine(float* __restrict__ lp)
{
  int idx = blockIdx.x * 256 + threadIdx.x;   // 32768 rows
  float l = lp[idx] + lp[32768 + idx];
  lp[idx] = 1.0f / l;
}

// prob[row][j] = p'[row][j] * linv[row] for valid j, else exact 0.
__global__ __launch_bounds__(256)
void rescale_prob(const float* __restrict__ linv, float* __restrict__ prob)
{
  const int row = blockIdx.x;                 // bn*1024 + i
  const int i = row & 1023;
  const float wgt = linv[row];
  const int lim = i + 1024;                   // j <= lim valid
  float* p = prob + ((size_t)row << 11) + threadIdx.x * 8;
  const int jb = threadIdx.x * 8;
  float4 a = *reinterpret_cast<const float4*>(p);
  float4 c = *reinterpret_cast<const float4*>(p + 4);
  float4 oa, oc;
  oa.x = (jb + 0 <= lim) ? a.x * wgt : 0.f;
  oa.y = (jb + 1 <= lim) ? a.y * wgt : 0.f;
  oa.z = (jb + 2 <= lim) ? a.z * wgt : 0.f;
  oa.w = (jb + 3 <= lim) ? a.w * wgt : 0.f;
  oc.x = (jb + 4 <= lim) ? c.x * wgt : 0.f;
  oc.y = (jb + 5 <= lim) ? c.y * wgt : 0.f;
  oc.z = (jb + 6 <= lim) ? c.z * wgt : 0.f;
  oc.w = (jb + 7 <= lim) ? c.w * wgt : 0.f;
  *reinterpret_cast<float4*>(p) = oa;
  *reinterpret_cast<float4*>(p + 4) = oc;
}

// ---------------------------------------------------------------------------
extern "C" void kernel_launch(void* const* d_in, const int* in_sizes, int n_in,
                              void* d_out, int out_size, void* d_ws, size_t ws_size,
                              hipStream_t stream)
{
  (void)in_sizes; (void)n_in; (void)out_size; (void)ws_size;
  const float* w    = (const float*)d_in[0];
  const float* r    = (const float*)d_in[1];
  const float* rwb  = (const float*)d_in[2];
  const float* rrb  = (const float*)d_in[3];
  const float* mems = (const float*)d_in[4];
  const float* Wqkv = (const float*)d_in[5];
  const float* Wr   = (const float*)d_in[6];
  const float* Wo   = (const float*)d_in[7];

  float* out  = (float*)d_out;
  float* prob = out + 2097152;

  // workspace: 67,371,008 B total (identical to the round-1/3 passing layout)
  short* Qwh = (short*)d_ws;
  short* Qwl = Qwh + 2097152;
  short* Qrh = Qwl + 2097152;
  short* Qrl = Qrh + 2097152;
  short* Kh  = Qrl + 2097152;
  short* Klo = Kh  + 4194304;
  short* Vb  = Klo + 4194304;
  short* RKh = Vb  + 4194304;
  short* RKl = RKh + 2097152;
  float* avp   = (float*)(RKl + 2097152);   // 2 x 2,097,152 floats
  float* lpart = avp + 4194304;             // 2 x 32,768 floats; linv in chunk 0

  gemm_mfma<0><<<dim3(24, 32), 256, 0, stream>>>(
      mems, w, Wqkv, Qwh, Qwl, Qrh, Qrl, Kh, Klo, Vb, nullptr, rwb, rrb, nullptr);
  gemm_mfma<1><<<dim3(8, 16), 256, 0, stream>>>(
      r, nullptr, Wr, RKh, RKl, nullptr, nullptr, nullptr, nullptr, nullptr,
      nullptr, nullptr, nullptr, nullptr);
  attn_fused<<<dim3(1024), 256, 0, stream>>>(
      Qwh, Qwl, Qrh, Qrl, Kh, Klo, RKh, RKl, Vb, prob, avp, lpart);
  l_combine<<<128, 256, 0, stream>>>(lpart);
  rescale_prob<<<32768, 256, 0, stream>>>(lpart, prob);
  gemm_mfma<2><<<dim3(8, 16), 256, 0, stream>>>(
      avp, avp + 2097152, Wo, nullptr, nullptr, nullptr, nullptr, nullptr, nullptr,
      nullptr, out, nullptr, nullptr, lpart);
}

// Round 14
// 617.856 us; speedup vs baseline: 1.3066x; 1.3066x over previous
//
#include <hip/hip_runtime.h>
#include <math.h>

#define NHh   16
#define QL    1024
#define KL    2048
#define SCALEh 0.125f

typedef __attribute__((ext_vector_type(8))) short s8v;
typedef __attribute__((ext_vector_type(4))) float f4v;

#define MFMA16(a,b,c) __builtin_amdgcn_mfma_f32_16x16x32_bf16((a),(b),(c),0,0,0)

__device__ __forceinline__ short f2bf(float x) {
  unsigned u = __float_as_uint(x);
  return (short)((u + 0x7fffu + ((u >> 16) & 1u)) >> 16);
}
__device__ __forceinline__ float bf2f(short s) {
  return __uint_as_float(((unsigned)(unsigned short)s) << 16);
}

// ---------------------------------------------------------------------------
// split-bf16 MFMA GEMM: C[m][n] = sum_k A[m][k]*Bmat[n][k], K=1024, tile 128x128
// MODE0: A=[mems;w] (M=4096), N=3072; epilogue: Qw/Qr hi/lo (+bias), K hi/lo, V^T bf16
// MODE1: A=r (M=2048), N=1024; epilogue: RK hi/lo [head][row][d]
// MODE2: A=(avp0+avp1)*linv_row; epilogue: out fp32
// LDS XOR swizzle: slot = row*8 + (kgroup ^ (row&7))
// ---------------------------------------------------------------------------
template<int MODE>
__global__ __launch_bounds__(256)
void gemm_mfma(const float* __restrict__ A0, const float* __restrict__ A1,
               const float* __restrict__ Bmat,
               short* __restrict__ P0h, short* __restrict__ P0l,
               short* __restrict__ P1h, short* __restrict__ P1l,
               short* __restrict__ P2h, short* __restrict__ P2l,
               short* __restrict__ P3,
               float* __restrict__ Ofp,
               const float* __restrict__ rwb, const float* __restrict__ rrb,
               const float* __restrict__ Wl)
{
  __shared__ short Ah[128*64];
  __shared__ short Al[128*64];
  __shared__ short Bh[128*64];
  __shared__ short Bl[128*64];
  const int n0 = blockIdx.x * 128, m0 = blockIdx.y * 128;
  if (MODE == 0 && n0 < 1024 && m0 < 2048) return;   // q rows t<1024 are discarded
  const int tid = threadIdx.x;
  const int L = tid & 63, lr = L & 15, lg = L >> 4;
  const int wid = tid >> 6, wm = wid >> 1, wn = wid & 1;
  const int srow = tid >> 1, sseg = tid & 1;

  const float* arow;
  const float* arow2 = nullptr;
  if (MODE == 0) {
    int m = m0 + srow;
    arow = (m < 2048) ? (A0 + (size_t)m * 1024) : (A1 + (size_t)(m - 2048) * 1024);
  } else {
    arow = A0 + (size_t)(m0 + srow) * 1024;
    if (MODE == 2) arow2 = A1 + (size_t)(m0 + srow) * 1024;
  }
  const float* brow = Bmat + (size_t)(n0 + srow) * 1024;

  const f4v fz = {0.f, 0.f, 0.f, 0.f};
  f4v acc[4][4];
#pragma unroll
  for (int a = 0; a < 4; ++a)
#pragma unroll
    for (int bq = 0; bq < 4; ++bq) acc[a][bq] = fz;

  for (int k0 = 0; k0 < 1024; k0 += 64) {
    __syncthreads();
    {
      float wgt = 1.0f;
      if (MODE == 2) {
        int m = m0 + srow;
        wgt = Wl[((size_t)((m & 1) * NHh) + (k0 >> 6)) * 1024 + (m >> 1)];
      }
      const float* pa = arow + k0 + sseg * 32;
#pragma unroll
      for (int v = 0; v < 4; ++v) {
        float4 f0 = *reinterpret_cast<const float4*>(pa + v * 8);
        float4 f1 = *reinterpret_cast<const float4*>(pa + v * 8 + 4);
        if (MODE == 2) {
          const float* pa2 = arow2 + k0 + sseg * 32;
          float4 g0 = *reinterpret_cast<const float4*>(pa2 + v * 8);
          float4 g1 = *reinterpret_cast<const float4*>(pa2 + v * 8 + 4);
          f0.x = (f0.x + g0.x) * wgt; f0.y = (f0.y + g0.y) * wgt;
          f0.z = (f0.z + g0.z) * wgt; f0.w = (f0.w + g0.w) * wgt;
          f1.x = (f1.x + g1.x) * wgt; f1.y = (f1.y + g1.y) * wgt;
          f1.z = (f1.z + g1.z) * wgt; f1.w = (f1.w + g1.w) * wgt;
        }
        float bf[8] = {f0.x, f0.y, f0.z, f0.w, f1.x, f1.y, f1.z, f1.w};
        s8v hi, lo;
#pragma unroll
        for (int e = 0; e < 8; ++e) {
          short h = f2bf(bf[e]); hi[e] = h; lo[e] = f2bf(bf[e] - bf2f(h));
        }
        int slot = srow * 8 + ((sseg * 4 + v) ^ (srow & 7));
        *reinterpret_cast<s8v*>(Ah + slot * 8) = hi;
        *reinterpret_cast<s8v*>(Al + slot * 8) = lo;
      }
      const float* pb = brow + k0 + sseg * 32;
#pragma unroll
      for (int v = 0; v < 4; ++v) {
        float4 f0 = *reinterpret_cast<const float4*>(pb + v * 8);
        float4 f1 = *reinterpret_cast<const float4*>(pb + v * 8 + 4);
        float bf[8] = {f0.x, f0.y, f0.z, f0.w, f1.x, f1.y, f1.z, f1.w};
        s8v hi, lo;
#pragma unroll
        for (int e = 0; e < 8; ++e) {
          short h = f2bf(bf[e]); hi[e] = h; lo[e] = f2bf(bf[e] - bf2f(h));
        }
        int slot = srow * 8 + ((sseg * 4 + v) ^ (srow & 7));
        *reinterpret_cast<s8v*>(Bh + slot * 8) = hi;
        *reinterpret_cast<s8v*>(Bl + slot * 8) = lo;
      }
    }
    __syncthreads();
#pragma unroll
    for (int ks = 0; ks < 2; ++ks) {
      s8v a_h[4], a_l[4], b_h[4], b_l[4];
#pragma unroll
      for (int x = 0; x < 4; ++x) {
        int ra = wm * 64 + x * 16 + lr;
        int sa = ra * 8 + ((ks * 4 + lg) ^ (ra & 7));
        a_h[x] = *reinterpret_cast<const s8v*>(Ah + sa * 8);
        a_l[x] = *reinterpret_cast<const s8v*>(Al + sa * 8);
        int rb = wn * 64 + x * 16 + lr;
        int sb = rb * 8 + ((ks * 4 + lg) ^ (rb & 7));
        b_h[x] = *reinterpret_cast<const s8v*>(Bh + sb * 8);
        b_l[x] = *reinterpret_cast<const s8v*>(Bl + sb * 8);
      }
#pragma unroll
      for (int mf = 0; mf < 4; ++mf)
#pragma unroll
        for (int nf = 0; nf < 4; ++nf) {
          acc[mf][nf] = MFMA16(a_l[mf], b_h[nf], acc[mf][nf]);
          acc[mf][nf] = MFMA16(a_h[mf], b_l[nf], acc[mf][nf]);
          acc[mf][nf] = MFMA16(a_h[mf], b_h[nf], acc[mf][nf]);
        }
    }
  }
  // ---- epilogue: C/D layout col=lane&15, row=(lane>>4)*4+reg (m89-verified)
  const int sec = (MODE == 0) ? (n0 >> 10) : 0;
#pragma unroll
  for (int mf = 0; mf < 4; ++mf)
#pragma unroll
    for (int nf = 0; nf < 4; ++nf) {
      const int n = n0 + wn * 64 + nf * 16 + lr;
#pragma unroll
      for (int r = 0; r < 4; ++r) {
        const int m = m0 + wm * 64 + mf * 16 + lg * 4 + r;
        float val = acc[mf][nf][r];
        if (MODE == 2) {
          Ofp[(size_t)m * 1024 + n] = val;
        } else if (MODE == 1) {
          int nn = n >> 6, d = n & 63;
          size_t idx = (((size_t)nn * KL + m) << 6) + d;
          short h = f2bf(val);
          P0h[idx] = h; P0l[idx] = f2bf(val - bf2f(h));
        } else {
          int b = m & 1, t = m >> 1;
          if (sec == 0) {                       // q section: t >= 1024 guaranteed
            int i = t - 1024;
            int nn = n >> 6, d = n & 63;
            size_t idx = (((size_t)(b * NHh + nn) * QL + i) << 6) + d;
            float qw = val + rwb[n];
            float qr = val + rrb[n];
            short h = f2bf(qw);
            P0h[idx] = h; P0l[idx] = f2bf(qw - bf2f(h));
            h = f2bf(qr);
            P1h[idx] = h; P1l[idx] = f2bf(qr - bf2f(h));
          } else if (sec == 1) {                // K
            int c = n - 1024; int nn = c >> 6, d = c & 63;
            size_t idx = (((size_t)(b * NHh + nn) * KL + t) << 6) + d;
            short h = f2bf(val);
            P2h[idx] = h; P2l[idx] = f2bf(val - bf2f(h));
          } else {                              // V^T single bf16 [bn][d][t]
            int c = n - 2048; int nn = c >> 6, d = c & 63;
            size_t idx = ((size_t)(b * NHh + nn) * 64 + d) * KL + t;
            P3[idx] = f2bf(val);
          }
        }
      }
    }
}

// ---------------------------------------------------------------------------
// Fused attention, single pass — EXACT round-3 pass1 shape (best measured
// per-tile efficiency: 247 us with inline just-in-time loads, 1 wave / 32
// q-rows), minus the stats read (p' = exp(s) unnormalized, r4+ scheme), plus
// the two isolated-positive deltas: XCD decode (FETCH 364->39 MB) and
// s_setprio (m191). No load batching (r9/r10/r12 all regressed or spilled),
// plain launch_bounds(64) to reproduce r3's ~180-VGPR allocation.
// Grid 2048 flat: xcd=orig&7 -> bn = xcd*4+..., iblk (32 x 32 rows), ch (2
// balanced j-chunks). Writes p' to prob, l partials, unnormalized AV partials.
// BD rel-shift: G[ir][c] = Qr_i * RK[BASE+c], BASE = 992-i0+j0; mf0 uses
// c in [16,95] (skip ci0), mf1 uses c in [0,79] (skip ci5);
// gather cl = 31 - mf*16 - ir16 + jf*16 + lr  (r3 refcheck-passed algebra).
// ---------------------------------------------------------------------------
__global__ __launch_bounds__(64)
void attn_fused(const short* __restrict__ Qwh, const short* __restrict__ Qwl,
                const short* __restrict__ Qrh, const short* __restrict__ Qrl,
                const short* __restrict__ Kh,  const short* __restrict__ Klo,
                const short* __restrict__ RKh, const short* __restrict__ RKl,
                const short* __restrict__ Vb,
                float* __restrict__ prob,
                float* __restrict__ avp,
                float* __restrict__ lpart)
{
  __shared__ float Gs[96 * 20];     // [c][i16] fp32, per-mf sequential reuse
  __shared__ short Ps[32 * 72];     // P tile bf16 for PV A-frags
  const int L = threadIdx.x;
  const int lr = L & 15, lg = L >> 4;
  // XCD-locality decode (bijection over 2048 = 8 xcd x 4 bnl x 64 rest)
  const int orig = blockIdx.x;
  const int xcd  = orig & 7;
  const int k2   = orig >> 3;              // 0..255
  const int bn   = xcd * 4 + (k2 >> 6);    // 0..31
  const int rest = k2 & 63;
  const int iblk = rest >> 1, ch = rest & 1;
  const int nh = bn & 15, b = bn >> 4;
  const int i0 = iblk * 32;
  const f4v fz = {0.f, 0.f, 0.f, 0.f};

  int T = ((i0 + 1055) >> 6) + 1; if (T > 32) T = 32;
  const int t0 = (ch * T) >> 1;
  const int t1 = ((ch + 1) * T) >> 1;

  // Q A-frags for both mf halves, held for the whole kernel
  s8v qw_h[2][2], qw_l[2][2], qr_h[2][2], qr_l[2][2];
#pragma unroll
  for (int mf = 0; mf < 2; ++mf)
#pragma unroll
    for (int ks = 0; ks < 2; ++ks) {
      size_t idx = (((size_t)bn * QL + i0 + mf * 16 + lr) << 6) + ks * 32 + lg * 8;
      qw_h[mf][ks] = *reinterpret_cast<const s8v*>(Qwh + idx);
      qw_l[mf][ks] = *reinterpret_cast<const s8v*>(Qwl + idx);
      qr_h[mf][ks] = *reinterpret_cast<const s8v*>(Qrh + idx);
      qr_l[mf][ks] = *reinterpret_cast<const s8v*>(Qrl + idx);
    }

  float lrun[2][4];
  f4v av[2][4];
#pragma unroll
  for (int mf = 0; mf < 2; ++mf)
#pragma unroll
    for (int r = 0; r < 4; ++r) { lrun[mf][r] = 0.f; av[mf][r] = fz; }

  float* probb = prob + (size_t)bn * QL * KL;

  for (int jt = t0; jt < t1; ++jt) {
    const int j0 = jt * 64;
    const int BASE = 992 - i0 + j0;
    // ---- BD window GEMM (inline loads, shared across both mf)
    f4v gacc[2][5];
#pragma unroll
    for (int mf = 0; mf < 2; ++mf)
#pragma unroll
      for (int gi = 0; gi < 5; ++gi) gacc[mf][gi] = fz;
    __builtin_amdgcn_s_setprio(1);
#pragma unroll
    for (int ci = 0; ci < 6; ++ci) {
      int rg = BASE + ci * 16 + lr;
      rg = rg < 0 ? 0 : (rg > 2047 ? 2047 : rg);  // clamped rows feed masked elems only
      size_t ridx = ((size_t)nh * KL + rg) << 6;
      s8v r_h[2], r_l[2];
#pragma unroll
      for (int ks = 0; ks < 2; ++ks) {
        r_h[ks] = *reinterpret_cast<const s8v*>(RKh + ridx + ks * 32 + lg * 8);
        r_l[ks] = *reinterpret_cast<const s8v*>(RKl + ridx + ks * 32 + lg * 8);
      }
#pragma unroll
      for (int mf = 0; mf < 2; ++mf) {
        if (mf == 0 && ci == 0) continue;   // mf0 uses c in [16,95]
        if (mf == 1 && ci == 5) continue;   // mf1 uses c in [0,79]
        const int gi = (mf == 0) ? (ci - 1) : ci;
#pragma unroll
        for (int ks = 0; ks < 2; ++ks) {
          gacc[mf][gi] = MFMA16(qr_l[mf][ks], r_h[ks], gacc[mf][gi]);
          gacc[mf][gi] = MFMA16(qr_h[mf][ks], r_l[ks], gacc[mf][gi]);
          gacc[mf][gi] = MFMA16(qr_h[mf][ks], r_h[ks], gacc[mf][gi]);
        }
      }
    }
    __builtin_amdgcn_s_setprio(0);
    // ---- per mf: spill G, AC GEMM (inline K loads), gather+exp+write
#pragma unroll
    for (int mf = 0; mf < 2; ++mf) {
#pragma unroll
      for (int gi = 0; gi < 5; ++gi) {
        int c = (mf == 0 ? 16 : 0) + gi * 16 + lr;
        *reinterpret_cast<f4v*>(Gs + c * 20 + lg * 4) = gacc[mf][gi];
      }
      f4v sfr[4];
      __builtin_amdgcn_s_setprio(1);
#pragma unroll
      for (int jf = 0; jf < 4; ++jf) {
        sfr[jf] = fz;
        size_t kidx = ((size_t)bn * KL + j0 + jf * 16 + lr) << 6;
#pragma unroll
        for (int ks = 0; ks < 2; ++ks) {
          s8v k_h = *reinterpret_cast<const s8v*>(Kh  + kidx + ks * 32 + lg * 8);
          s8v k_l = *reinterpret_cast<const s8v*>(Klo + kidx + ks * 32 + lg * 8);
          sfr[jf] = MFMA16(qw_l[mf][ks], k_h, sfr[jf]);
          sfr[jf] = MFMA16(qw_h[mf][ks], k_l, sfr[jf]);
          sfr[jf] = MFMA16(qw_h[mf][ks], k_h, sfr[jf]);
        }
      }
      __builtin_amdgcn_s_setprio(0);
#pragma unroll
      for (int jf = 0; jf < 4; ++jf) {
#pragma unroll
        for (int r = 0; r < 4; ++r) {
          const int ir16 = lg * 4 + r;
          const int i = i0 + mf * 16 + ir16;
          const int j = j0 + jf * 16 + lr;
          const int cl = 31 - mf * 16 - ir16 + jf * 16 + lr;
          float s = (sfr[jf][r] + Gs[cl * 20 + ir16]) * SCALEh;
          float p = (j <= i + 1024) ? __expf(s) : 0.f;
          probb[(size_t)i * KL + j] = p;
          Ps[(mf * 16 + ir16) * 72 + jf * 16 + lr] = f2bf(p);
          lrun[mf][r] += p;
        }
      }
    }
    // ---- PV: inline V loads shared across both mf (r3 shape)
    __builtin_amdgcn_s_setprio(1);
#pragma unroll
    for (int ks = 0; ks < 2; ++ks) {
      s8v pa[2];
#pragma unroll
      for (int mf = 0; mf < 2; ++mf)
        pa[mf] = *reinterpret_cast<const s8v*>(Ps + (mf * 16 + lr) * 72 + ks * 32 + lg * 8);
#pragma unroll
      for (int df = 0; df < 4; ++df) {
        s8v vfr = *reinterpret_cast<const s8v*>(
            Vb + ((size_t)bn * 64 + df * 16 + lr) * KL + j0 + ks * 32 + lg * 8);
#pragma unroll
        for (int mf = 0; mf < 2; ++mf)
          av[mf][df] = MFMA16(pa[mf], vfr, av[mf][df]);
      }
    }
    __builtin_amdgcn_s_setprio(0);
  }

  // ---- l partials: sum over the 16 lanes (lr) sharing each row
#pragma unroll
  for (int mf = 0; mf < 2; ++mf)
#pragma unroll
    for (int r = 0; r < 4; ++r) {
      float l = lrun[mf][r];
#pragma unroll
      for (int mk = 1; mk <= 8; mk <<= 1) l += __shfl_xor(l, mk, 64);
      if (lr == 0) {
        int i = i0 + mf * 16 + lg * 4 + r;
        lpart[(size_t)ch * 32768 + (size_t)bn * QL + i] = l;
      }
    }
  // ---- AV' partials
#pragma unroll
  for (int mf = 0; mf < 2; ++mf)
#pragma unroll
    for (int df = 0; df < 4; ++df)
#pragma unroll
      for (int r = 0; r < 4; ++r) {
        int i = i0 + mf * 16 + lg * 4 + r;
        int d = df * 16 + lr;
        avp[(size_t)ch * 2097152 + ((size_t)i * 2 + b) * 1024 + nh * 64 + d] = av[mf][df][r];
      }
}

// linv[row] = 1 / (lpart0[row] + lpart1[row]), in place into lpart0
__global__ __launch_bounds__(256)
void l_combine(float* __restrict__ lp)
{
  int idx = blockIdx.x * 256 + threadIdx.x;   // 32768 rows
  float l = lp[idx] + lp[32768 + idx];
  lp[idx] = 1.0f / l;
}

// prob[row][j] = p'[row][j] * linv[row] for valid j, else exact 0.
__global__ __launch_bounds__(256)
void rescale_prob(const float* __restrict__ linv, float* __restrict__ prob)
{
  const int row = blockIdx.x;                 // bn*1024 + i
  const int i = row & 1023;
  const float wgt = linv[row];
  const int lim = i + 1024;                   // j <= lim valid
  float* p = prob + ((size_t)row << 11) + threadIdx.x * 8;
  const int jb = threadIdx.x * 8;
  float4 a = *reinterpret_cast<const float4*>(p);
  float4 c = *reinterpret_cast<const float4*>(p + 4);
  float4 oa, oc;
  oa.x = (jb + 0 <= lim) ? a.x * wgt : 0.f;
  oa.y = (jb + 1 <= lim) ? a.y * wgt : 0.f;
  oa.z = (jb + 2 <= lim) ? a.z * wgt : 0.f;
  oa.w = (jb + 3 <= lim) ? a.w * wgt : 0.f;
  oc.x = (jb + 4 <= lim) ? c.x * wgt : 0.f;
  oc.y = (jb + 5 <= lim) ? c.y * wgt : 0.f;
  oc.z = (jb + 6 <= lim) ? c.z * wgt : 0.f;
  oc.w = (jb + 7 <= lim) ? c.w * wgt : 0.f;
  *reinterpret_cast<float4*>(p) = oa;
  *reinterpret_cast<float4*>(p + 4) = oc;
}

// ---------------------------------------------------------------------------
extern "C" void kernel_launch(void* const* d_in, const int* in_sizes, int n_in,
                              void* d_out, int out_size, void* d_ws, size_t ws_size,
                              hipStream_t stream)
{
  (void)in_sizes; (void)n_in; (void)out_size; (void)ws_size;
  const float* w    = (const float*)d_in[0];
  const float* r    = (const float*)d_in[1];
  const float* rwb  = (const float*)d_in[2];
  const float* rrb  = (const float*)d_in[3];
  const float* mems = (const float*)d_in[4];
  const float* Wqkv = (const float*)d_in[5];
  const float* Wr   = (const float*)d_in[6];
  const float* Wo   = (const float*)d_in[7];

  float* out  = (float*)d_out;
  float* prob = out + 2097152;

  // workspace: 67,371,008 B total (identical to the round-1/3 passing layout)
  short* Qwh = (short*)d_ws;
  short* Qwl = Qwh + 2097152;
  short* Qrh = Qwl + 2097152;
  short* Qrl = Qrh + 2097152;
  short* Kh  = Qrl + 2097152;
  short* Klo = Kh  + 4194304;
  short* Vb  = Klo + 4194304;
  short* RKh = Vb  + 4194304;
  short* RKl = RKh + 2097152;
  float* avp   = (float*)(RKl + 2097152);   // 2 x 2,097,152 floats
  float* lpart = avp + 4194304;             // 2 x 32,768 floats; linv in chunk 0

  gemm_mfma<0><<<dim3(24, 32), 256, 0, stream>>>(
      mems, w, Wqkv, Qwh, Qwl, Qrh, Qrl, Kh, Klo, Vb, nullptr, rwb, rrb, nullptr);
  gemm_mfma<1><<<dim3(8, 16), 256, 0, stream>>>(
      r, nullptr, Wr, RKh, RKl, nullptr, nullptr, nullptr, nullptr, nullptr,
      nullptr, nullptr, nullptr, nullptr);
  attn_fused<<<dim3(2048), 64, 0, stream>>>(
      Qwh, Qwl, Qrh, Qrl, Kh, Klo, RKh, RKl, Vb, prob, avp, lpart);
  l_combine<<<128, 256, 0, stream>>>(lpart);
  rescale_prob<<<32768, 256, 0, stream>>>(lpart, prob);
  gemm_mfma<2><<<dim3(8, 16), 256, 0, stream>>>(
      avp, avp + 2097152, Wo, nullptr, nullptr, nullptr, nullptr, nullptr, nullptr,
      nullptr, out, nullptr, nullptr, lpart);
}

// Round 15
// 613.795 us; speedup vs baseline: 1.3153x; 1.0066x over previous
//
#include <hip/hip_runtime.h>
#include <math.h>

#define NHh   16
#define QL    1024
#define KL    2048
#define SCALEh 0.125f

typedef __attribute__((ext_vector_type(8))) short s8v;
typedef __attribute__((ext_vector_type(4))) float f4v;

#define MFMA16(a,b,c) __builtin_amdgcn_mfma_f32_16x16x32_bf16((a),(b),(c),0,0,0)

__device__ __forceinline__ short f2bf(float x) {
  unsigned u = __float_as_uint(x);
  return (short)((u + 0x7fffu + ((u >> 16) & 1u)) >> 16);
}
__device__ __forceinline__ float bf2f(short s) {
  return __uint_as_float(((unsigned)(unsigned short)s) << 16);
}

// ---------------------------------------------------------------------------
// split-bf16 MFMA GEMM: C[m][n] = sum_k A[m][k]*Bmat[n][k], K=1024, tile 128x128
// MODE0: A=[mems;w] (M=4096), N=3072; epilogue: Qw/Qr hi/lo (+bias), K hi/lo, V^T bf16
// MODE1: A=r (M=2048), N=1024; epilogue: RK hi/lo [head][row][d]
// MODE2: A=avp*linv_row (single buffer); epilogue: out fp32
// LDS XOR swizzle: slot = row*8 + (kgroup ^ (row&7))
// ---------------------------------------------------------------------------
template<int MODE>
__global__ __launch_bounds__(256)
void gemm_mfma(const float* __restrict__ A0, const float* __restrict__ A1,
               const float* __restrict__ Bmat,
               short* __restrict__ P0h, short* __restrict__ P0l,
               short* __restrict__ P1h, short* __restrict__ P1l,
               short* __restrict__ P2h, short* __restrict__ P2l,
               short* __restrict__ P3,
               float* __restrict__ Ofp,
               const float* __restrict__ rwb, const float* __restrict__ rrb,
               const float* __restrict__ Wl)
{
  __shared__ short Ah[128*64];
  __shared__ short Al[128*64];
  __shared__ short Bh[128*64];
  __shared__ short Bl[128*64];
  const int n0 = blockIdx.x * 128, m0 = blockIdx.y * 128;
  if (MODE == 0 && n0 < 1024 && m0 < 2048) return;   // q rows t<1024 are discarded
  const int tid = threadIdx.x;
  const int L = tid & 63, lr = L & 15, lg = L >> 4;
  const int wid = tid >> 6, wm = wid >> 1, wn = wid & 1;
  const int srow = tid >> 1, sseg = tid & 1;

  const float* arow;
  if (MODE == 0) {
    int m = m0 + srow;
    arow = (m < 2048) ? (A0 + (size_t)m * 1024) : (A1 + (size_t)(m - 2048) * 1024);
  } else {
    arow = A0 + (size_t)(m0 + srow) * 1024;
  }
  const float* brow = Bmat + (size_t)(n0 + srow) * 1024;

  const f4v fz = {0.f, 0.f, 0.f, 0.f};
  f4v acc[4][4];
#pragma unroll
  for (int a = 0; a < 4; ++a)
#pragma unroll
    for (int bq = 0; bq < 4; ++bq) acc[a][bq] = fz;

  for (int k0 = 0; k0 < 1024; k0 += 64) {
    __syncthreads();
    {
      float wgt = 1.0f;
      if (MODE == 2) {
        int m = m0 + srow;
        wgt = Wl[((size_t)((m & 1) * NHh) + (k0 >> 6)) * 1024 + (m >> 1)];
      }
      const float* pa = arow + k0 + sseg * 32;
#pragma unroll
      for (int v = 0; v < 4; ++v) {
        float4 f0 = *reinterpret_cast<const float4*>(pa + v * 8);
        float4 f1 = *reinterpret_cast<const float4*>(pa + v * 8 + 4);
        if (MODE == 2) {
          f0.x *= wgt; f0.y *= wgt; f0.z *= wgt; f0.w *= wgt;
          f1.x *= wgt; f1.y *= wgt; f1.z *= wgt; f1.w *= wgt;
        }
        float bf[8] = {f0.x, f0.y, f0.z, f0.w, f1.x, f1.y, f1.z, f1.w};
        s8v hi, lo;
#pragma unroll
        for (int e = 0; e < 8; ++e) {
          short h = f2bf(bf[e]); hi[e] = h; lo[e] = f2bf(bf[e] - bf2f(h));
        }
        int slot = srow * 8 + ((sseg * 4 + v) ^ (srow & 7));
        *reinterpret_cast<s8v*>(Ah + slot * 8) = hi;
        *reinterpret_cast<s8v*>(Al + slot * 8) = lo;
      }
      const float* pb = brow + k0 + sseg * 32;
#pragma unroll
      for (int v = 0; v < 4; ++v) {
        float4 f0 = *reinterpret_cast<const float4*>(pb + v * 8);
        float4 f1 = *reinterpret_cast<const float4*>(pb + v * 8 + 4);
        float bf[8] = {f0.x, f0.y, f0.z, f0.w, f1.x, f1.y, f1.z, f1.w};
        s8v hi, lo;
#pragma unroll
        for (int e = 0; e < 8; ++e) {
          short h = f2bf(bf[e]); hi[e] = h; lo[e] = f2bf(bf[e] - bf2f(h));
        }
        int slot = srow * 8 + ((sseg * 4 + v) ^ (srow & 7));
        *reinterpret_cast<s8v*>(Bh + slot * 8) = hi;
        *reinterpret_cast<s8v*>(Bl + slot * 8) = lo;
      }
    }
    __syncthreads();
#pragma unroll
    for (int ks = 0; ks < 2; ++ks) {
      s8v a_h[4], a_l[4], b_h[4], b_l[4];
#pragma unroll
      for (int x = 0; x < 4; ++x) {
        int ra = wm * 64 + x * 16 + lr;
        int sa = ra * 8 + ((ks * 4 + lg) ^ (ra & 7));
        a_h[x] = *reinterpret_cast<const s8v*>(Ah + sa * 8);
        a_l[x] = *reinterpret_cast<const s8v*>(Al + sa * 8);
        int rb = wn * 64 + x * 16 + lr;
        int sb = rb * 8 + ((ks * 4 + lg) ^ (rb & 7));
        b_h[x] = *reinterpret_cast<const s8v*>(Bh + sb * 8);
        b_l[x] = *reinterpret_cast<const s8v*>(Bl + sb * 8);
      }
#pragma unroll
      for (int mf = 0; mf < 4; ++mf)
#pragma unroll
        for (int nf = 0; nf < 4; ++nf) {
          acc[mf][nf] = MFMA16(a_l[mf], b_h[nf], acc[mf][nf]);
          acc[mf][nf] = MFMA16(a_h[mf], b_l[nf], acc[mf][nf]);
          acc[mf][nf] = MFMA16(a_h[mf], b_h[nf], acc[mf][nf]);
        }
    }
  }
  // ---- epilogue: C/D layout col=lane&15, row=(lane>>4)*4+reg (m89-verified)
  const int sec = (MODE == 0) ? (n0 >> 10) : 0;
#pragma unroll
  for (int mf = 0; mf < 4; ++mf)
#pragma unroll
    for (int nf = 0; nf < 4; ++nf) {
      const int n = n0 + wn * 64 + nf * 16 + lr;
#pragma unroll
      for (int r = 0; r < 4; ++r) {
        const int m = m0 + wm * 64 + mf * 16 + lg * 4 + r;
        float val = acc[mf][nf][r];
        if (MODE == 2) {
          Ofp[(size_t)m * 1024 + n] = val;
        } else if (MODE == 1) {
          int nn = n >> 6, d = n & 63;
          size_t idx = (((size_t)nn * KL + m) << 6) + d;
          short h = f2bf(val);
          P0h[idx] = h; P0l[idx] = f2bf(val - bf2f(h));
        } else {
          int b = m & 1, t = m >> 1;
          if (sec == 0) {                       // q section: t >= 1024 guaranteed
            int i = t - 1024;
            int nn = n >> 6, d = n & 63;
            size_t idx = (((size_t)(b * NHh + nn) * QL + i) << 6) + d;
            float qw = val + rwb[n];
            float qr = val + rrb[n];
            short h = f2bf(qw);
            P0h[idx] = h; P0l[idx] = f2bf(qw - bf2f(h));
            h = f2bf(qr);
            P1h[idx] = h; P1l[idx] = f2bf(qr - bf2f(h));
          } else if (sec == 1) {                // K
            int c = n - 1024; int nn = c >> 6, d = c & 63;
            size_t idx = (((size_t)(b * NHh + nn) * KL + t) << 6) + d;
            short h = f2bf(val);
            P2h[idx] = h; P2l[idx] = f2bf(val - bf2f(h));
          } else {                              // V^T single bf16 [bn][d][t]
            int c = n - 2048; int nn = c >> 6, d = c & 63;
            size_t idx = ((size_t)(b * NHh + nn) * 64 + d) * KL + t;
            P3[idx] = f2bf(val);
          }
        }
      }
    }
}

// ---------------------------------------------------------------------------
// Fused attention. Per-WAVE code = round-14's proven 226-us shape (1 wave owns
// 32 q-rows, inline just-in-time loads, setprio, r3-refchecked rel-shift
// algebra). This round packs 4 INDEPENDENT such waves per 256-thread block to
// fix residency (r14: OccupancyPercent 8.6% — 1-wave workgroups don't pack;
// HW workgroup slots, not VGPR, were the limit). Block = one (bn, iblk); wave
// wv covers valid-tile quarter [wv*T/4,(wv+1)*T/4). No barriers in main loop;
// LDS partitioned per wave (12 KB each). End-of-kernel LDS reduction (2
// barriers total) combines the 4 waves' av and l: avp becomes a single fully
// summed buffer and linv = 1/l is written directly (l_combine deleted).
// Grid 1024 = 8 xcd x 4 bn x 32 iblk (XCD L2 locality, FETCH 32 MB confirmed).
// BD rel-shift: G[ir][c] = Qr_i * RK[BASE+c], BASE = 992-i0+j0; mf0 uses
// c in [16,95] (skip ci0), mf1 uses c in [0,79] (skip ci5);
// gather cl = 31 - mf*16 - ir16 + jf*16 + lr.
// ---------------------------------------------------------------------------
__global__ __launch_bounds__(256)
void attn_fused(const short* __restrict__ Qwh, const short* __restrict__ Qwl,
                const short* __restrict__ Qrh, const short* __restrict__ Qrl,
                const short* __restrict__ Kh,  const short* __restrict__ Klo,
                const short* __restrict__ RKh, const short* __restrict__ RKl,
                const short* __restrict__ Vb,
                float* __restrict__ prob,
                float* __restrict__ avp,
                float* __restrict__ linv)
{
  __shared__ __align__(16) char SM[49152];   // per wave: Gs 7680 B + Ps 4608 B
  const int tid = threadIdx.x;
  const int wv = tid >> 6;
  const int L = tid & 63, lr = L & 15, lg = L >> 4;
  // XCD-locality decode (bijection over 1024 = 8 xcd x 4 bnl x 32 iblk)
  const int orig = blockIdx.x;
  const int xcd  = orig & 7;
  const int k2   = orig >> 3;              // 0..127
  const int bn   = xcd * 4 + (k2 >> 5);    // 0..31
  const int iblk = k2 & 31;
  const int nh = bn & 15, b = bn >> 4;
  const int i0 = iblk * 32;
  const f4v fz = {0.f, 0.f, 0.f, 0.f};

  int T = ((i0 + 1055) >> 6) + 1; if (T > 32) T = 32;
  const int t0 = (wv * T) >> 2;
  const int t1 = ((wv + 1) * T) >> 2;

  float* gs = (float*)(SM + wv * 12288);            // [96][20] fp32
  short* ps = (short*)(SM + wv * 12288 + 7680);     // [32][72] bf16

  // Q A-frags for both mf halves, held for the whole kernel
  s8v qw_h[2][2], qw_l[2][2], qr_h[2][2], qr_l[2][2];
#pragma unroll
  for (int mf = 0; mf < 2; ++mf)
#pragma unroll
    for (int ks = 0; ks < 2; ++ks) {
      size_t idx = (((size_t)bn * QL + i0 + mf * 16 + lr) << 6) + ks * 32 + lg * 8;
      qw_h[mf][ks] = *reinterpret_cast<const s8v*>(Qwh + idx);
      qw_l[mf][ks] = *reinterpret_cast<const s8v*>(Qwl + idx);
      qr_h[mf][ks] = *reinterpret_cast<const s8v*>(Qrh + idx);
      qr_l[mf][ks] = *reinterpret_cast<const s8v*>(Qrl + idx);
    }

  float lrun[2][4];
  f4v av[2][4];
#pragma unroll
  for (int mf = 0; mf < 2; ++mf)
#pragma unroll
    for (int r = 0; r < 4; ++r) { lrun[mf][r] = 0.f; av[mf][r] = fz; }

  float* probb = prob + (size_t)bn * QL * KL;

  for (int jt = t0; jt < t1; ++jt) {
    const int j0 = jt * 64;
    const int BASE = 992 - i0 + j0;
    // ---- BD window GEMM (inline loads, shared across both mf)
    f4v gacc[2][5];
#pragma unroll
    for (int mf = 0; mf < 2; ++mf)
#pragma unroll
      for (int gi = 0; gi < 5; ++gi) gacc[mf][gi] = fz;
    __builtin_amdgcn_s_setprio(1);
#pragma unroll
    for (int ci = 0; ci < 6; ++ci) {
      int rg = BASE + ci * 16 + lr;
      rg = rg < 0 ? 0 : (rg > 2047 ? 2047 : rg);  // clamped rows feed masked elems only
      size_t ridx = ((size_t)nh * KL + rg) << 6;
      s8v r_h[2], r_l[2];
#pragma unroll
      for (int ks = 0; ks < 2; ++ks) {
        r_h[ks] = *reinterpret_cast<const s8v*>(RKh + ridx + ks * 32 + lg * 8);
        r_l[ks] = *reinterpret_cast<const s8v*>(RKl + ridx + ks * 32 + lg * 8);
      }
#pragma unroll
      for (int mf = 0; mf < 2; ++mf) {
        if (mf == 0 && ci == 0) continue;   // mf0 uses c in [16,95]
        if (mf == 1 && ci == 5) continue;   // mf1 uses c in [0,79]
        const int gi = (mf == 0) ? (ci - 1) : ci;
#pragma unroll
        for (int ks = 0; ks < 2; ++ks) {
          gacc[mf][gi] = MFMA16(qr_l[mf][ks], r_h[ks], gacc[mf][gi]);
          gacc[mf][gi] = MFMA16(qr_h[mf][ks], r_l[ks], gacc[mf][gi]);
          gacc[mf][gi] = MFMA16(qr_h[mf][ks], r_h[ks], gacc[mf][gi]);
        }
      }
    }
    __builtin_amdgcn_s_setprio(0);
    // ---- per mf: spill G, AC GEMM (inline K loads), gather+exp+write
#pragma unroll
    for (int mf = 0; mf < 2; ++mf) {
#pragma unroll
      for (int gi = 0; gi < 5; ++gi) {
        int c = (mf == 0 ? 16 : 0) + gi * 16 + lr;
        *reinterpret_cast<f4v*>(gs + c * 20 + lg * 4) = gacc[mf][gi];
      }
      f4v sfr[4];
      __builtin_amdgcn_s_setprio(1);
#pragma unroll
      for (int jf = 0; jf < 4; ++jf) {
        sfr[jf] = fz;
        size_t kidx = ((size_t)bn * KL + j0 + jf * 16 + lr) << 6;
#pragma unroll
        for (int ks = 0; ks < 2; ++ks) {
          s8v k_h = *reinterpret_cast<const s8v*>(Kh  + kidx + ks * 32 + lg * 8);
          s8v k_l = *reinterpret_cast<const s8v*>(Klo + kidx + ks * 32 + lg * 8);
          sfr[jf] = MFMA16(qw_l[mf][ks], k_h, sfr[jf]);
          sfr[jf] = MFMA16(qw_h[mf][ks], k_l, sfr[jf]);
          sfr[jf] = MFMA16(qw_h[mf][ks], k_h, sfr[jf]);
        }
      }
      __builtin_amdgcn_s_setprio(0);
#pragma unroll
      for (int jf = 0; jf < 4; ++jf) {
#pragma unroll
        for (int r = 0; r < 4; ++r) {
          const int ir16 = lg * 4 + r;
          const int i = i0 + mf * 16 + ir16;
          const int j = j0 + jf * 16 + lr;
          const int cl = 31 - mf * 16 - ir16 + jf * 16 + lr;
          float s = (sfr[jf][r] + gs[cl * 20 + ir16]) * SCALEh;
          float p = (j <= i + 1024) ? __expf(s) : 0.f;
          probb[(size_t)i * KL + j] = p;
          ps[(mf * 16 + ir16) * 72 + jf * 16 + lr] = f2bf(p);
          lrun[mf][r] += p;
        }
      }
    }
    // ---- PV: inline V loads shared across both mf
    __builtin_amdgcn_s_setprio(1);
#pragma unroll
    for (int ks = 0; ks < 2; ++ks) {
      s8v pa[2];
#pragma unroll
      for (int mf = 0; mf < 2; ++mf)
        pa[mf] = *reinterpret_cast<const s8v*>(ps + (mf * 16 + lr) * 72 + ks * 32 + lg * 8);
#pragma unroll
      for (int df = 0; df < 4; ++df) {
        s8v vfr = *reinterpret_cast<const s8v*>(
            Vb + ((size_t)bn * 64 + df * 16 + lr) * KL + j0 + ks * 32 + lg * 8);
#pragma unroll
        for (int mf = 0; mf < 2; ++mf)
          av[mf][df] = MFMA16(pa[mf], vfr, av[mf][df]);
      }
    }
    __builtin_amdgcn_s_setprio(0);
  }

  // ---- cross-wave reduction of av and l (SM reused; all main loops done)
  __syncthreads();
  float* red = (float*)SM;                  // wave w>0: av 2048 f + l 32 f at (w-1)*2080
  // per-wave l reduce over the 16 lanes sharing each row
  float lred[2][4];
#pragma unroll
  for (int mf = 0; mf < 2; ++mf)
#pragma unroll
    for (int r = 0; r < 4; ++r) {
      float l = lrun[mf][r];
#pragma unroll
      for (int mk = 1; mk <= 8; mk <<= 1) l += __shfl_xor(l, mk, 64);
      lred[mf][r] = l;
    }
  if (wv > 0) {
    float* ra = red + (wv - 1) * 2080;
#pragma unroll
    for (int mf = 0; mf < 2; ++mf)
#pragma unroll
      for (int df = 0; df < 4; ++df)
        *reinterpret_cast<f4v*>(ra + L * 32 + mf * 16 + df * 4) = av[mf][df];
    if (lr == 0) {
#pragma unroll
      for (int mf = 0; mf < 2; ++mf)
#pragma unroll
        for (int r = 0; r < 4; ++r)
          ra[2048 + mf * 16 + lg * 4 + r] = lred[mf][r];
    }
  }
  __syncthreads();
  if (wv == 0) {
#pragma unroll
    for (int mf = 0; mf < 2; ++mf)
#pragma unroll
      for (int df = 0; df < 4; ++df) {
        f4v t = av[mf][df];
#pragma unroll
        for (int w = 1; w < 4; ++w)
          t += *reinterpret_cast<const f4v*>(red + (w - 1) * 2080 + L * 32 + mf * 16 + df * 4);
#pragma unroll
        for (int r = 0; r < 4; ++r) {
          int i = i0 + mf * 16 + lg * 4 + r;
          int d = df * 16 + lr;
          avp[((size_t)i * 2 + b) * 1024 + nh * 64 + d] = t[r];
        }
      }
    if (lr == 0) {
#pragma unroll
      for (int mf = 0; mf < 2; ++mf)
#pragma unroll
        for (int r = 0; r < 4; ++r) {
          float l = lred[mf][r];
#pragma unroll
          for (int w = 1; w < 4; ++w)
            l += red[(w - 1) * 2080 + 2048 + mf * 16 + lg * 4 + r];
          linv[(size_t)bn * QL + i0 + mf * 16 + lg * 4 + r] = 1.0f / l;
        }
    }
  }
}

// prob[row][j] = p'[row][j] * linv[row] for valid j, else exact 0.
__global__ __launch_bounds__(256)
void rescale_prob(const float* __restrict__ linv, float* __restrict__ prob)
{
  const int row = blockIdx.x;                 // bn*1024 + i
  const int i = row & 1023;
  const float wgt = linv[row];
  const int lim = i + 1024;                   // j <= lim valid
  float* p = prob + ((size_t)row << 11) + threadIdx.x * 8;
  const int jb = threadIdx.x * 8;
  float4 a = *reinterpret_cast<const float4*>(p);
  float4 c = *reinterpret_cast<const float4*>(p + 4);
  float4 oa, oc;
  oa.x = (jb + 0 <= lim) ? a.x * wgt : 0.f;
  oa.y = (jb + 1 <= lim) ? a.y * wgt : 0.f;
  oa.z = (jb + 2 <= lim) ? a.z * wgt : 0.f;
  oa.w = (jb + 3 <= lim) ? a.w * wgt : 0.f;
  oc.x = (jb + 4 <= lim) ? c.x * wgt : 0.f;
  oc.y = (jb + 5 <= lim) ? c.y * wgt : 0.f;
  oc.z = (jb + 6 <= lim) ? c.z * wgt : 0.f;
  oc.w = (jb + 7 <= lim) ? c.w * wgt : 0.f;
  *reinterpret_cast<float4*>(p) = oa;
  *reinterpret_cast<float4*>(p + 4) = oc;
}

// ---------------------------------------------------------------------------
extern "C" void kernel_launch(void* const* d_in, const int* in_sizes, int n_in,
                              void* d_out, int out_size, void* d_ws, size_t ws_size,
                              hipStream_t stream)
{
  (void)in_sizes; (void)n_in; (void)out_size; (void)ws_size;
  const float* w    = (const float*)d_in[0];
  const float* r    = (const float*)d_in[1];
  const float* rwb  = (const float*)d_in[2];
  const float* rrb  = (const float*)d_in[3];
  const float* mems = (const float*)d_in[4];
  const float* Wqkv = (const float*)d_in[5];
  const float* Wr   = (const float*)d_in[6];
  const float* Wo   = (const float*)d_in[7];

  float* out  = (float*)d_out;
  float* prob = out + 2097152;

  // workspace (within the 67 MB footprint used since round 1)
  short* Qwh = (short*)d_ws;
  short* Qwl = Qwh + 2097152;
  short* Qrh = Qwl + 2097152;
  short* Qrl = Qrh + 2097152;
  short* Kh  = Qrl + 2097152;
  short* Klo = Kh  + 4194304;
  short* Vb  = Klo + 4194304;
  short* RKh = Vb  + 4194304;
  short* RKl = RKh + 2097152;
  float* avp  = (float*)(RKl + 2097152);    // 2,097,152 floats (fully summed)
  float* linv = avp + 2097152;              // 32,768 floats

  gemm_mfma<0><<<dim3(24, 32), 256, 0, stream>>>(
      mems, w, Wqkv, Qwh, Qwl, Qrh, Qrl, Kh, Klo, Vb, nullptr, rwb, rrb, nullptr);
  gemm_mfma<1><<<dim3(8, 16), 256, 0, stream>>>(
      r, nullptr, Wr, RKh, RKl, nullptr, nullptr, nullptr, nullptr, nullptr,
      nullptr, nullptr, nullptr, nullptr);
  attn_fused<<<dim3(1024), 256, 0, stream>>>(
      Qwh, Qwl, Qrh, Qrl, Kh, Klo, RKh, RKl, Vb, prob, avp, linv);
  rescale_prob<<<32768, 256, 0, stream>>>(linv, prob);
  gemm_mfma<2><<<dim3(8, 16), 256, 0, stream>>>(
      avp, nullptr, Wo, nullptr, nullptr, nullptr, nullptr, nullptr, nullptr,
      nullptr, out, nullptr, nullptr, linv);
}